// Round 7
// baseline (121.117 us; speedup 1.0000x reference)
//
#include <hip/hip_runtime.h>

// LocalConnectivity: diamond (L1-ball radius 5) circular convolution over
// (B=64, H=512, W=512) fp32, weight per L1-distance d: w_d = d_in[1][d-1].
//
// Decomposition (exact):
//   h_a[r][j] = sum_{|b| <= 5-a} w_{a+|b|} * s[r][(j+b)&511]   (h_0 excludes b=0)
//   out[i][j] = h_0[i][j] + sum_{a=1..5} (h_a[i-a][j] + h_a[i+a][j])
//
// Ledger: R1 forced-cap spills 217us | R2 direct-global 67us latency-bound |
//   R3 6-slot ring + per-iter __syncthreads: 43.4us | R4 forced launch_bounds
//   spills 157us (never force) | R5 scalar LDS reads 49us LDS-issue-bound |
//   R6 per-iter counted vmcnt 54us | R7 whole-strip stage + ONE __syncthreads:
//   ~40us (stage/compute serial, CU-wide phase lockstep) | R8 wave-autonomous
//   DMA ring 110us | R9 counted-vmcnt chunk barriers 52.5us.
//   META: every hand-asm wait structure regressed; every plain-__syncthreads
//   bulk structure landed ~40us. R10 therefore uses ONLY __syncthreads.
// R10 (this): R7 split into a 2-phase software double-buffer:
//   issue DMA rows 0..12 -> __syncthreads (drains phase-1 only; nothing else
//   outstanding) -> issue DMA rows 13..25 (in flight UNDER phase-1 compute;
//   LDS regions disjoint, no ring reuse) -> compute rows 0..12 ->
//   __syncthreads (vmcnt(0) drains phase-2) -> compute rows 13..25.
//   Hides ~half the stage time under compute; worst case (backend orders
//   phase-1 ds_reads behind phase-2 DMAs) degrades to R7, not below.
//   Plus XCD-aware bijective remap (2048%8==0): each XCD gets 8 contiguous
//   batches x all 32 strips -> adjacent strips (10 shared halo rows) hit the
//   same XCD's L2. Compute body byte-identical to R6/R7/R9 (verified).

#define LC_H 512
#define LC_W 512
#define LC_TY 16
#define LC_NT 256            // threads per block; each owns 2 columns
#define LC_NR (LC_TY + 10)   // 26 source rows per strip
#define LC_SPLIT 13          // rows in phase 1
#define LC_NSTRIP (LC_H / LC_TY)   // 32
#define LC_NWG (LC_NSTRIP * 64)    // 2048 workgroups

typedef const __attribute__((address_space(1))) void* lc_gvp;
typedef __attribute__((address_space(3))) void* lc_lvp;

__global__ __launch_bounds__(LC_NT)
void LocalConnectivity_kernel(const float* __restrict__ in,
                              const float* __restrict__ wp,
                              float* __restrict__ out) {
    const int t = threadIdx.x;            // column-pair index 0..255

    // XCD-aware bijective remap (m204 form; LC_NWG % 8 == 0):
    // dispatch id lin -> xcd = lin&7 round-robin (HW heuristic). Give XCD k
    // the contiguous work chunk [k*256, (k+1)*256): 8 batches x 32 strips.
    // Adjacent strips of one batch then co-reside on one XCD -> halo rows
    // (10 of 26) L2-hit instead of L3/HBM.
    const int lin = (int)blockIdx.x + LC_NSTRIP * (int)blockIdx.y;
    const int wg  = (lin & 7) * (LC_NWG / 8) + (lin >> 3);
    const int strip = wg & (LC_NSTRIP - 1);
    const int b     = wg >> 5;            // wg / 32
    const int r0 = strip * LC_TY;         // first output row of strip

    const float w1 = wp[0], w2 = wp[1], w3 = wp[2], w4 = wp[3], w5 = wp[4];

    const float* __restrict__ src = in + (size_t)b * (LC_H * LC_W);
    float* __restrict__ dst = out + (size_t)b * (LC_H * LC_W);

    __shared__ __attribute__((aligned(16))) float lds[LC_NR * LC_W]; // 52 KB

    // DMA source row j (grid row (r0+j-5)&511) -> LDS row j, 2 insts (256B
    // per wave-inst, 4 waves cover the 2KB row). Linear lane-contiguous dest.
#define LC_ISSUE(j) do {                                                     \
        const float* rp_ = src + ((r0 + (j) - 5) & (LC_H - 1)) * LC_W;       \
        float* lp_ = &lds[(j) * LC_W];                                       \
        __builtin_amdgcn_global_load_lds((lc_gvp)(rp_ + t),                  \
                                         (lc_lvp)(lp_ + t), 4, 0, 0);        \
        __builtin_amdgcn_global_load_lds((lc_gvp)(rp_ + LC_NT + t),          \
                                         (lc_lvp)(lp_ + LC_NT + t), 4, 0, 0);\
    } while (0)

    // ---- phase-1 staging: rows 0..12
#pragma unroll
    for (int j = 0; j < LC_SPLIT; ++j) LC_ISSUE(j);

    float acc[11][2];
#pragma unroll
    for (int k = 0; k < 11; ++k) { acc[k][0] = 0.f; acc[k][1] = 0.f; }

    // compute body for source row rr (rr compile-time under full unroll:
    // all guards and %11 ring indices fold; acc stays in named registers).
    auto body = [&](const int rr) {
        // halo cols 2t-6 .. 2t+7 of source row rr: 7 x ds_read_b64
        const float* slotp = &lds[rr * LC_W];
        float v[14];
#pragma unroll
        for (int o = 0; o < 7; ++o) {
            const int cb = (t + o - 3) & (LC_NT - 1);
            const float2 f = *reinterpret_cast<const float2*>(slotp + cb * 2);
            v[o * 2 + 0] = f.x;
            v[o * 2 + 1] = f.y;
        }

        const int r_off = rr - 5;
#pragma unroll
        for (int q = 0; q < 2; ++q) {
            const float p0 = v[6 + q];
            const float p1 = v[5 + q] + v[7 + q];
            const float p2 = v[4 + q] + v[8 + q];
            const float p3 = v[3 + q] + v[9 + q];
            const float p4 = v[2 + q] + v[10 + q];
            const float p5 = v[1 + q] + v[11 + q];

            float hv;
            hv = w1 * p1 + w2 * p2 + w3 * p3 + w4 * p4 + w5 * p5;
            if (r_off >= 0 && r_off < LC_TY) acc[r_off % 11][q] += hv;
            hv = w1 * p0 + w2 * p1 + w3 * p2 + w4 * p3 + w5 * p4;
            {
                const int op = r_off + 1, om = r_off - 1;
                if (op >= 0 && op < LC_TY) acc[op % 11][q] += hv;
                if (om >= 0 && om < LC_TY) acc[om % 11][q] += hv;
            }
            hv = w2 * p0 + w3 * p1 + w4 * p2 + w5 * p3;
            {
                const int op = r_off + 2, om = r_off - 2;
                if (op >= 0 && op < LC_TY) acc[op % 11][q] += hv;
                if (om >= 0 && om < LC_TY) acc[om % 11][q] += hv;
            }
            hv = w3 * p0 + w4 * p1 + w5 * p2;
            {
                const int op = r_off + 3, om = r_off - 3;
                if (op >= 0 && op < LC_TY) acc[op % 11][q] += hv;
                if (om >= 0 && om < LC_TY) acc[om % 11][q] += hv;
            }
            hv = w4 * p0 + w5 * p1;
            {
                const int op = r_off + 4, om = r_off - 4;
                if (op >= 0 && op < LC_TY) acc[op % 11][q] += hv;
                if (om >= 0 && om < LC_TY) acc[om % 11][q] += hv;
            }
            hv = w5 * p0;
            {
                const int op = r_off + 5, om = r_off - 5;
                if (op >= 0 && op < LC_TY) acc[op % 11][q] += hv;
                if (om >= 0 && om < LC_TY) acc[om % 11][q] += hv;
            }
        }

        // output row oc = rr - 10 complete after this source row
        const int oc = rr - 10;
        if (oc >= 0 && oc < LC_TY) {
            const int slot = oc % 11;
            float2 f;
            f.x = acc[slot][0];
            f.y = acc[slot][1];
            *reinterpret_cast<float2*>(dst + (size_t)(r0 + oc) * LC_W + t * 2) = f;
            acc[slot][0] = 0.f;
            acc[slot][1] = 0.f;
        }
    };

    // Barrier 1: __syncthreads drains vmcnt(0) -> rows 0..12 resident.
    // (Only phase-1 loads are outstanding here, so nothing extra is waited.)
    __syncthreads();

    // ---- phase-2 staging: rows 13..25, in flight UNDER phase-1 compute.
    // LDS writes (rows >=13) are disjoint from phase-1 reads (rows <=12).
#pragma unroll
    for (int j = LC_SPLIT; j < LC_NR; ++j) LC_ISSUE(j);

    // ---- phase-1 compute: source rows 0..12 (completes output rows 0..2)
#pragma unroll
    for (int rr = 0; rr < LC_SPLIT; ++rr) body(rr);

    // Barrier 2: drains phase-2 loads (vmcnt(0)) + cross-wave visibility.
    __syncthreads();

    // ---- phase-2 compute: source rows 13..25 (output rows 3..15)
#pragma unroll
    for (int rr = LC_SPLIT; rr < LC_NR; ++rr) body(rr);

#undef LC_ISSUE
}

extern "C" void kernel_launch(void* const* d_in, const int* in_sizes, int n_in,
                              void* d_out, int out_size, void* d_ws, size_t ws_size,
                              hipStream_t stream) {
    const float* grid_spikes = (const float*)d_in[0];       // 64*512*512 fp32
    const float* distance_weights = (const float*)d_in[1];  // 5 fp32
    float* out = (float*)d_out;

    dim3 grid(LC_NSTRIP, 64);  // 32 strips x 64 batches = 2048 blocks
    dim3 block(LC_NT);
    LocalConnectivity_kernel<<<grid, block, 0, stream>>>(grid_spikes, distance_weights, out);
}

// Round 8
// 120.603 us; speedup vs baseline: 1.0043x; 1.0043x over previous
//
#include <hip/hip_runtime.h>

// LocalConnectivity: diamond (L1-ball radius 5) circular convolution over
// (B=64, H=512, W=512) fp32, weight per L1-distance d: w_d = d_in[1][d-1].
//
// Decomposition (exact):
//   h_a[r][j] = sum_{|b| <= 5-a} w_{a+|b|} * s[r][(j+b)&511]   (h_0 excludes b=0)
//   out[i][j] = h_0[i][j] + sum_{a=1..5} (h_a[i-a][j] + h_a[i+a][j])
//
// Ledger: R1 forced-cap spills 217 | R2 direct-global 67 | R3 ring+per-iter
//   sync 43.4 | R4 forced bounds spills 157 | R5 scalar LDS reads 49 |
//   R6 per-iter counted vmcnt 54 | R7 stage-all + ONE sync ~40 (best; serial
//   stage/compute, cohort lockstep) | R8 per-wave DMA ring 110 | R9 counted
//   chunk vmcnt 52.5 | R10 same-array double-buffer 55.7: compiler cannot
//   prove ds_read(lds) disjoint from in-flight global_load_lds(lds) -> it
//   inserts vmcnt(0) before the reads -> serialized; BUT XCD locality
//   worked (FETCH 53->33 MB).
//   META: __syncthreads-only structures land ~40; all hand-asm waits lose.
// R11 (this): persistent 1-block/CU rolling double-buffer with TWO
//   statically distinct __shared__ arrays (bufA/bufB -> trivially no-alias
//   -> no conservative vmcnt before compute's ds_reads while the other
//   buffer's DMAs fly). Grid = 256 blocks (104 KB LDS forces 1/CU); each
//   block owns 8 vertically-adjacent strips of one batch:
//     issue strip0->A; sync;
//     4x{ issue s+1->B; compute(s,A); sync;   // sync drains B's DMAs,
//         issue s+2->A; compute(s+1,B); sync; } // after a strip of cover
//   Every buffer ref statically A or B (no runtime select - preserves AA).
//   DMA cover = full strip compute (~1.8k cyc >> HBM latency). Adjacent
//   strips share 10 halo rows fetched by the SAME CU -> L2-hot re-reads.
//   __launch_bounds__(256,1): VGPRs are free at 1 wave/SIMD (no spill by
//   construction). Compute body byte-identical to R6/R7 (verified).

#define LC_H 512
#define LC_W 512
#define LC_TY 16
#define LC_NT 256            // threads per block; each owns 2 columns
#define LC_NR (LC_TY + 10)   // 26 source rows per strip window
#define LC_SPB 8             // strips per block (persistent)

typedef const __attribute__((address_space(1))) void* lc_gvp;
typedef __attribute__((address_space(3))) void* lc_lvp;

__global__ __launch_bounds__(LC_NT, 1)
void LocalConnectivity_kernel(const float* __restrict__ in,
                              const float* __restrict__ wp,
                              float* __restrict__ out) {
    const int t = threadIdx.x;           // column-pair index 0..255
    const int blk = blockIdx.x;          // 0..255, one per CU
    const int b = blk >> 2;              // batch 0..63
    const int s0 = (blk & 3) * LC_SPB;   // first strip (of 32) for this block

    const float w1 = wp[0], w2 = wp[1], w3 = wp[2], w4 = wp[3], w5 = wp[4];

    const float* __restrict__ src = in + (size_t)b * (LC_H * LC_W);
    float* __restrict__ dst = out + (size_t)b * (LC_H * LC_W);

    // TWO distinct LDS objects: basic-AA proves ds_read(bufA) independent of
    // outstanding global_load_lds writes to bufB (and vice versa).
    __shared__ __attribute__((aligned(16))) float bufA[LC_NR * LC_W]; // 52 KB
    __shared__ __attribute__((aligned(16))) float bufB[LC_NR * LC_W]; // 52 KB

    // stage the 26-row window of strip (s0+s) into lbuf: 52 DMA insts,
    // issued back-to-back; linear lane-contiguous LDS dests.
    auto issue = [&](float* __restrict__ lbuf, const int s) {
        const int r0 = (s0 + s) * LC_TY;
#pragma unroll
        for (int j = 0; j < LC_NR; ++j) {
            const float* rp = src + ((r0 + j - 5) & (LC_H - 1)) * LC_W;
            float* lp = lbuf + j * LC_W;
            __builtin_amdgcn_global_load_lds((lc_gvp)(rp + t),
                                             (lc_lvp)(lp + t), 4, 0, 0);
            __builtin_amdgcn_global_load_lds((lc_gvp)(rp + LC_NT + t),
                                             (lc_lvp)(lp + LC_NT + t), 4, 0, 0);
        }
    };

    float acc[11][2];
#pragma unroll
    for (int k = 0; k < 11; ++k) { acc[k][0] = 0.f; acc[k][1] = 0.f; }

    // compute the 16 output rows of strip (s0+s) from lbuf. rr compile-time
    // under full unroll: guards and %11 ring indices fold; acc in registers.
    // acc is all-zero again on exit (every output store zeroes its slot).
    auto compute = [&](const float* __restrict__ lbuf, const int s) {
        const int r0 = (s0 + s) * LC_TY;
#pragma unroll
        for (int rr = 0; rr < LC_NR; ++rr) {
            // halo cols 2t-6 .. 2t+7 of source row rr: 7 x ds_read_b64
            const float* slotp = lbuf + rr * LC_W;
            float v[14];
#pragma unroll
            for (int o = 0; o < 7; ++o) {
                const int cb = (t + o - 3) & (LC_NT - 1);
                const float2 f =
                    *reinterpret_cast<const float2*>(slotp + cb * 2);
                v[o * 2 + 0] = f.x;
                v[o * 2 + 1] = f.y;
            }

            const int r_off = rr - 5;
#pragma unroll
            for (int q = 0; q < 2; ++q) {
                const float p0 = v[6 + q];
                const float p1 = v[5 + q] + v[7 + q];
                const float p2 = v[4 + q] + v[8 + q];
                const float p3 = v[3 + q] + v[9 + q];
                const float p4 = v[2 + q] + v[10 + q];
                const float p5 = v[1 + q] + v[11 + q];

                float hv;
                hv = w1 * p1 + w2 * p2 + w3 * p3 + w4 * p4 + w5 * p5;
                if (r_off >= 0 && r_off < LC_TY) acc[r_off % 11][q] += hv;
                hv = w1 * p0 + w2 * p1 + w3 * p2 + w4 * p3 + w5 * p4;
                {
                    const int op = r_off + 1, om = r_off - 1;
                    if (op >= 0 && op < LC_TY) acc[op % 11][q] += hv;
                    if (om >= 0 && om < LC_TY) acc[om % 11][q] += hv;
                }
                hv = w2 * p0 + w3 * p1 + w4 * p2 + w5 * p3;
                {
                    const int op = r_off + 2, om = r_off - 2;
                    if (op >= 0 && op < LC_TY) acc[op % 11][q] += hv;
                    if (om >= 0 && om < LC_TY) acc[om % 11][q] += hv;
                }
                hv = w3 * p0 + w4 * p1 + w5 * p2;
                {
                    const int op = r_off + 3, om = r_off - 3;
                    if (op >= 0 && op < LC_TY) acc[op % 11][q] += hv;
                    if (om >= 0 && om < LC_TY) acc[om % 11][q] += hv;
                }
                hv = w4 * p0 + w5 * p1;
                {
                    const int op = r_off + 4, om = r_off - 4;
                    if (op >= 0 && op < LC_TY) acc[op % 11][q] += hv;
                    if (om >= 0 && om < LC_TY) acc[om % 11][q] += hv;
                }
                hv = w5 * p0;
                {
                    const int op = r_off + 5, om = r_off - 5;
                    if (op >= 0 && op < LC_TY) acc[op % 11][q] += hv;
                    if (om >= 0 && om < LC_TY) acc[om % 11][q] += hv;
                }
            }

            // output row oc = rr - 10 complete after this source row
            const int oc = rr - 10;
            if (oc >= 0 && oc < LC_TY) {
                const int slot = oc % 11;
                float2 f;
                f.x = acc[slot][0];
                f.y = acc[slot][1];
                *reinterpret_cast<float2*>(
                    dst + (size_t)(r0 + oc) * LC_W + t * 2) = f;
                acc[slot][0] = 0.f;
                acc[slot][1] = 0.f;
            }
        }
    };

    // ---- rolling pipeline over 8 strips, A/B statically alternated
    issue(bufA, 0);
    __syncthreads();   // drains strip-0 DMAs

    for (int pr = 0; pr < LC_SPB / 2; ++pr) {
        const int s = 2 * pr;
        if (s + 1 < LC_SPB) issue(bufB, s + 1);   // fly under compute(A)
        compute(bufA, s);
        __syncthreads();   // drains B's DMAs (+ cross-wave visibility)
        if (s + 2 < LC_SPB) issue(bufA, s + 2);   // fly under compute(B)
        compute(bufB, s + 1);
        __syncthreads();   // drains A's DMAs
    }
}

extern "C" void kernel_launch(void* const* d_in, const int* in_sizes, int n_in,
                              void* d_out, int out_size, void* d_ws, size_t ws_size,
                              hipStream_t stream) {
    const float* grid_spikes = (const float*)d_in[0];       // 64*512*512 fp32
    const float* distance_weights = (const float*)d_in[1];  // 5 fp32
    float* out = (float*)d_out;

    dim3 grid(256);   // 64 batches x 4 column-of-8-strips groups; 1 block/CU
    dim3 block(LC_NT);
    LocalConnectivity_kernel<<<grid, block, 0, stream>>>(grid_spikes, distance_weights, out);
}